// Round 6
// baseline (317.057 us; speedup 1.0000x reference)
//
#include <hip/hip_runtime.h>
#include <hip/hip_fp16.h>
#include <math.h>

#define N_NODES 50000
#define N_EDGES 800000
#define D 64
#define SCAN_B 256
#define NBLK1 ((N_NODES + SCAN_B - 1) / SCAN_B)   // 196
#define GEMM_BLOCKS ((N_NODES + 63) / 64)         // 782
#define FILL_BLOCKS ((N_EDGES + 255) / 256)       // 3125

// ---------------------------------------------------------------------------
// CSR build helpers
// ---------------------------------------------------------------------------
__global__ void k_zero(int* __restrict__ cnt) {
    int i = blockIdx.x * blockDim.x + threadIdx.x;
    if (i < N_NODES) cnt[i] = 0;
}

__global__ void k_count(const int* __restrict__ dst, int* __restrict__ cnt) {
    int e = blockIdx.x * blockDim.x + threadIdx.x;
    if (e < N_EDGES) atomicAdd(&cnt[dst[e]], 1);
}

// per-block exclusive scan of cnt -> row_start (partial), block totals -> bsum
__global__ void k_scan1(const int* __restrict__ cnt, int* __restrict__ row_start,
                        int* __restrict__ bsum) {
    __shared__ int s[SCAN_B];
    int t = threadIdx.x;
    int i = blockIdx.x * SCAN_B + t;
    int v = (i < N_NODES) ? cnt[i] : 0;
    s[t] = v;
    __syncthreads();
    #pragma unroll
    for (int off = 1; off < SCAN_B; off <<= 1) {
        int u = (t >= off) ? s[t - off] : 0;
        __syncthreads();
        s[t] += u;
        __syncthreads();
    }
    if (i < N_NODES) row_start[i] = s[t] - v;      // exclusive within block
    if (t == SCAN_B - 1) bsum[blockIdx.x] = s[t];  // block total
}

__global__ void k_scan2(int* __restrict__ bsum) {
    __shared__ int s[SCAN_B];
    int t = threadIdx.x;
    int v = (t < NBLK1) ? bsum[t] : 0;
    s[t] = v;
    __syncthreads();
    #pragma unroll
    for (int off = 1; off < SCAN_B; off <<= 1) {
        int u = (t >= off) ? s[t - off] : 0;
        __syncthreads();
        s[t] += u;
        __syncthreads();
    }
    if (t < NBLK1) bsum[t] = s[t] - v;             // exclusive
}

// add block offsets; cursor = row_start; dinv = rsqrt(cnt + 1); sentinel at N
__global__ void k_scan3(int* __restrict__ row_start, const int* __restrict__ bsum,
                        const int* __restrict__ cnt, int* __restrict__ cursor,
                        float* __restrict__ dinv) {
    int i = blockIdx.x * blockDim.x + threadIdx.x;
    if (i < N_NODES) {
        int rs = row_start[i] + bsum[i / SCAN_B];
        row_start[i] = rs;
        cursor[i] = rs;
        dinv[i] = rsqrtf((float)cnt[i] + 1.0f);
        if (i == N_NODES - 1) row_start[N_NODES] = N_EDGES;
    }
}

// ---------------------------------------------------------------------------
// GEMM body: hWs[row,:] = (h[row,:] @ W) * dinv[row], fp16 out.
// 256 threads / 64 rows per block. Per-thread 4x4 output tile (16 acc regs).
// W in LDS [k][col]; h in LDS TRANSPOSED [k][row] (+4 pad). Per k: one b128
// of W (4 distinct addrs/wave, conflict-free) + one b128 of hT (2-way, free)
// feeding 16 FMAs -> FMA-bound, no giant register arrays for the compiler
// to bail on (R5 lesson: wreg[64] silently demoted, VGPR_Count=52).
// ---------------------------------------------------------------------------
__device__ __forceinline__ void gemm64_body(const float* __restrict__ h, int hstride,
                                            const float* __restrict__ W,
                                            const float* __restrict__ dinv,
                                            __half* __restrict__ hWh, int row0) {
    __shared__ float Ws[64][64];      // 16 KB
    __shared__ float hsT[64][68];     // 17.4 KB, [k][row] padded +4
    int tid = threadIdx.x;

    // stage W: 64 rows x 16 float4, coalesced
    const float4* W4 = (const float4*)W;
    for (int i = tid; i < 64 * 16; i += 256) {
        float4 w = W4[i];
        *(float4*)&Ws[i >> 4][(i & 15) * 4] = w;
    }
    // stage h transposed: read float4 rows, write 4 scalars
    for (int i = tid; i < 64 * 16; i += 256) {
        int r = i >> 4, c4 = (i & 15) * 4;
        int gr = row0 + r;
        float4 hv = make_float4(0.f, 0.f, 0.f, 0.f);
        if (gr < N_NODES) hv = *(const float4*)&h[(size_t)gr * hstride + c4];
        hsT[c4 + 0][r] = hv.x;
        hsT[c4 + 1][r] = hv.y;
        hsT[c4 + 2][r] = hv.z;
        hsT[c4 + 3][r] = hv.w;
    }
    __syncthreads();

    int r0 = (tid & 15) * 4;     // output rows r0..r0+3
    int c0 = (tid >> 4) * 4;     // output cols c0..c0+3
    float4 a0 = make_float4(0.f, 0.f, 0.f, 0.f);
    float4 a1 = a0, a2 = a0, a3 = a0;
    #pragma unroll
    for (int k = 0; k < 64; ++k) {
        float4 wv = *(const float4*)&Ws[k][c0];
        float4 hv = *(const float4*)&hsT[k][r0];
        a0.x += hv.x * wv.x; a0.y += hv.x * wv.y; a0.z += hv.x * wv.z; a0.w += hv.x * wv.w;
        a1.x += hv.y * wv.x; a1.y += hv.y * wv.y; a1.z += hv.y * wv.z; a1.w += hv.y * wv.w;
        a2.x += hv.z * wv.x; a2.y += hv.z * wv.y; a2.z += hv.z * wv.z; a2.w += hv.z * wv.w;
        a3.x += hv.w * wv.x; a3.y += hv.w * wv.y; a3.z += hv.w * wv.z; a3.w += hv.w * wv.w;
    }

    #pragma unroll
    for (int i = 0; i < 4; ++i) {
        int gr = row0 + r0 + i;
        if (gr >= N_NODES) break;
        float4 v = (i == 0) ? a0 : (i == 1) ? a1 : (i == 2) ? a2 : a3;
        float sc = dinv[gr];
        __half2 p01 = __floats2half2_rn(v.x * sc, v.y * sc);
        __half2 p23 = __floats2half2_rn(v.z * sc, v.w * sc);
        uint2 st;
        st.x = *(unsigned*)&p01;
        st.y = *(unsigned*)&p23;
        *(uint2*)&hWh[((size_t)gr << 6) + c0] = st;
    }
}

__global__ __launch_bounds__(256) void k_gemm64(const float* __restrict__ h, int hstride,
                                                const float* __restrict__ W,
                                                const float* __restrict__ dinv,
                                                __half* __restrict__ hWh) {
    gemm64_body(h, hstride, W, dinv, hWh, blockIdx.x * 64);
}

// ---------------------------------------------------------------------------
// Merged: blocks [0, GEMM_BLOCKS) do layer-1 GEMM; the rest fill the CSR.
// ---------------------------------------------------------------------------
__global__ __launch_bounds__(256) void k_gemm1_fill(
        const float* __restrict__ x, const float* __restrict__ W1,
        const float* __restrict__ dinv, __half* __restrict__ hWh,
        const int* __restrict__ src, const int* __restrict__ dst,
        int* __restrict__ cursor, int* __restrict__ csr_src) {
    if (blockIdx.x < GEMM_BLOCKS) {
        gemm64_body(x, D, W1, dinv, hWh, blockIdx.x * 64);
    } else {
        int e = (blockIdx.x - GEMM_BLOCKS) * 256 + threadIdx.x;
        if (e < N_EDGES) {
            int s = src[e], d = dst[e];
            int pos = atomicAdd(&cursor[d], 1);
            csr_src[pos] = s;
        }
    }
}

// ---------------------------------------------------------------------------
// Fused aggregate: half-wave (32 lanes) per node, lane owns a feature PAIR.
// acc = hWs[node] + sum_e hWs[src] ; out = b + dinv[node]*acc ; elu ; store.
// Unroll 8 for gather-chain ILP.
// ---------------------------------------------------------------------------
__global__ __launch_bounds__(256) void k_gather_elu(
        const unsigned* __restrict__ hW2,      // [N][32] half2-packed (pre-scaled)
        const int* __restrict__ row_start,     // N+1 entries
        const int* __restrict__ csr_src,
        const float* __restrict__ dinv,
        const float* __restrict__ bias,
        float* __restrict__ out, int col_off) {
    int gid = blockIdx.x * blockDim.x + threadIdx.x;
    int node = gid >> 5;
    if (node >= N_NODES) return;
    int fp = gid & 31;
    unsigned sv = hW2[((size_t)node << 5) + fp];
    float2 sf = __half22float2(*(const __half2*)&sv);
    float acc0 = sf.x, acc1 = sf.y;            // self message (pre-scaled)
    int j   = row_start[node];
    int end = row_start[node + 1];
    for (; j + 8 <= end; j += 8) {
        int s0 = csr_src[j],     s1 = csr_src[j + 1];
        int s2 = csr_src[j + 2], s3 = csr_src[j + 3];
        int s4 = csr_src[j + 4], s5 = csr_src[j + 5];
        int s6 = csr_src[j + 6], s7 = csr_src[j + 7];
        unsigned v0 = hW2[((size_t)s0 << 5) + fp];
        unsigned v1 = hW2[((size_t)s1 << 5) + fp];
        unsigned v2 = hW2[((size_t)s2 << 5) + fp];
        unsigned v3 = hW2[((size_t)s3 << 5) + fp];
        unsigned v4 = hW2[((size_t)s4 << 5) + fp];
        unsigned v5 = hW2[((size_t)s5 << 5) + fp];
        unsigned v6 = hW2[((size_t)s6 << 5) + fp];
        unsigned v7 = hW2[((size_t)s7 << 5) + fp];
        float2 f0 = __half22float2(*(const __half2*)&v0);
        float2 f1 = __half22float2(*(const __half2*)&v1);
        float2 f2 = __half22float2(*(const __half2*)&v2);
        float2 f3 = __half22float2(*(const __half2*)&v3);
        float2 f4 = __half22float2(*(const __half2*)&v4);
        float2 f5 = __half22float2(*(const __half2*)&v5);
        float2 f6 = __half22float2(*(const __half2*)&v6);
        float2 f7 = __half22float2(*(const __half2*)&v7);
        acc0 += ((f0.x + f1.x) + (f2.x + f3.x)) + ((f4.x + f5.x) + (f6.x + f7.x));
        acc1 += ((f0.y + f1.y) + (f2.y + f3.y)) + ((f4.y + f5.y) + (f6.y + f7.y));
    }
    for (; j + 2 <= end; j += 2) {
        int s0 = csr_src[j], s1 = csr_src[j + 1];
        unsigned v0 = hW2[((size_t)s0 << 5) + fp];
        unsigned v1 = hW2[((size_t)s1 << 5) + fp];
        float2 f0 = __half22float2(*(const __half2*)&v0);
        float2 f1 = __half22float2(*(const __half2*)&v1);
        acc0 += f0.x + f1.x;
        acc1 += f0.y + f1.y;
    }
    if (j < end) {
        int s0 = csr_src[j];
        unsigned v0 = hW2[((size_t)s0 << 5) + fp];
        float2 f0 = __half22float2(*(const __half2*)&v0);
        acc0 += f0.x;
        acc1 += f0.y;
    }
    float dn = dinv[node];
    float2 bb = *(const float2*)&bias[2 * fp];
    acc0 = bb.x + dn * acc0;
    acc1 = bb.y + dn * acc1;
    acc0 = (acc0 > 0.0f) ? acc0 : expm1f(acc0);
    acc1 = (acc1 > 0.0f) ? acc1 : expm1f(acc1);
    *(float2*)&out[(size_t)node * (3 * D) + col_off + 2 * fp] = make_float2(acc0, acc1);
}

extern "C" void kernel_launch(void* const* d_in, const int* in_sizes, int n_in,
                              void* d_out, int out_size, void* d_ws, size_t ws_size,
                              hipStream_t stream) {
    const float* x   = (const float*)d_in[0];
    const int*   ei  = (const int*)d_in[1];
    const int*   src = ei;
    const int*   dst = ei + N_EDGES;
    const float* W[3] = {(const float*)d_in[2], (const float*)d_in[4], (const float*)d_in[6]};
    const float* b[3] = {(const float*)d_in[3], (const float*)d_in[5], (const float*)d_in[7]};
    float* out = (float*)d_out;

    // workspace layout
    char* ws = (char*)d_ws;
    float* dinv      = (float*)ws;                          ws += N_NODES * 4;
    int*   cnt       = (int*)ws;                            ws += N_NODES * 4;
    int*   cursor    = (int*)ws;                            ws += N_NODES * 4;
    int*   row_start = (int*)ws;                            ws += (N_NODES + 1) * 4;
    int*   bsum      = (int*)ws;                            ws += SCAN_B * 4;
    int*   csr_src   = (int*)ws;                            ws += (size_t)N_EDGES * 4;
    __half* hWh      = (__half*)ws;                         // N*D halves

    // degree + scan (CSR skeleton)
    k_zero <<<(N_NODES + 255) / 256, 256, 0, stream>>>(cnt);
    k_count<<<(N_EDGES + 255) / 256, 256, 0, stream>>>(dst, cnt);
    k_scan1<<<NBLK1, SCAN_B, 0, stream>>>(cnt, row_start, bsum);
    k_scan2<<<1, SCAN_B, 0, stream>>>(bsum);
    k_scan3<<<(N_NODES + 255) / 256, 256, 0, stream>>>(row_start, bsum, cnt, cursor, dinv);

    // layer 1 GEMM (pre-scaled by dinv) overlapped with CSR fill
    k_gemm1_fill<<<GEMM_BLOCKS + FILL_BLOCKS, 256, 0, stream>>>(
        x, W[0], dinv, hWh, src, dst, cursor, csr_src);

    long long gthreads = (long long)N_NODES * 32;
    int gather_grid = (int)((gthreads + 255) / 256);

    // layer 1 aggregate
    k_gather_elu<<<gather_grid, 256, 0, stream>>>(
        (const unsigned*)hWh, row_start, csr_src, dinv, b[0], out, 0);

    // layers 2, 3
    for (int l = 1; l < 3; ++l) {
        k_gemm64<<<GEMM_BLOCKS, 256, 0, stream>>>(out + (l - 1) * D, 3 * D, W[l], dinv, hWh);
        k_gather_elu<<<gather_grid, 256, 0, stream>>>(
            (const unsigned*)hWh, row_start, csr_src, dinv, b[l], out, l * D);
    }
}